// Round 3
// baseline (229.859 us; speedup 1.0000x reference)
//
#include <hip/hip_runtime.h>
#include <math.h>

#define NM 5
#define NBATCH 65536
#define NCHUNKS 50         // 5 models * 10 chunks (4 W1, 4 W2, 2 W3-padded)

typedef float f32x16 __attribute__((ext_vector_type(16)));
typedef float f32x4  __attribute__((ext_vector_type(4)));
typedef short short8 __attribute__((ext_vector_type(8)));
typedef unsigned int uint4v __attribute__((ext_vector_type(4)));
typedef unsigned int uint2v __attribute__((ext_vector_type(2)));

__device__ __forceinline__ short8 u2s(uint4v v) { union { uint4v u; short8 s; } t; t.u = v; return t.s; }

__device__ __forceinline__ void plswap(unsigned &a, unsigned &b) {
#if __has_builtin(__builtin_amdgcn_permlane32_swap)
  uint2v r = __builtin_amdgcn_permlane32_swap(a, b, false, false);
  a = r[0]; b = r[1];
#else
  unsigned ta = (unsigned)__shfl_xor((int)a, 32, 64);
  unsigned tb = (unsigned)__shfl_xor((int)b, 32, 64);
  bool h0 = ((threadIdx.x & 63) < 32);
  unsigned na = h0 ? a : tb;
  unsigned nb = h0 ? ta : b;
  a = na; b = nb;
#endif
}

// ---- prep: weights -> per-lane A-fragment image (direct global-load layout) -----------
// chunk c10 (= m*10+c) is 16 KiB: [hi plane 8 KiB][lo plane 8 KiB];
// within a plane: frag(kk, lane) at kk*1024 + lane*16 holds W[row=lane&31][16kk+8*(lane>>5)+j]
__global__ void prep_weights(const float* __restrict__ W1, const float* __restrict__ W2,
                             const float* __restrict__ W3, char* __restrict__ img) {
  int id = blockIdx.x * 256 + threadIdx.x;       // one thread per (c10, kk, lane)
  if (id >= NCHUNKS * 8 * 64) return;
  int lane = id & 63; int kk = (id >> 6) & 7; int c10 = id >> 9;
  int m = c10 / 10, c = c10 % 10;
  int g_rel = lane & 31, half = lane >> 5;
  int k0 = kk * 16 + half * 8;
  const float* src = nullptr;
  if (c < 4)      { int g = c * 32 + g_rel;       src = W1 + ((size_t)m * 128 + g) * 128 + k0; }
  else if (c < 8) { int g = (c - 4) * 32 + g_rel; src = W2 + ((size_t)m * 128 + g) * 128 + k0; }
  else            { int g = (c - 8) * 32 + g_rel; if (g < 36) src = W3 + ((size_t)m * 36 + g) * 128 + k0; }
  union { short8 v; unsigned short s[8]; } hi, lo;
#pragma unroll
  for (int j = 0; j < 8; ++j) {
    float v = src ? src[j] : 0.0f;
    unsigned u = __float_as_uint(v);
    unsigned h = u & 0xFFFF0000u;
    float l = v - __uint_as_float(h);
    hi.s[j] = (unsigned short)(h >> 16);
    lo.s[j] = (unsigned short)(__float_as_uint(l) >> 16);
  }
  char* dst = img + (size_t)c10 * 16384 + kk * 1024 + lane * 16;
  *(short8*)dst = hi.v;
  *(short8*)(dst + 8192) = lo.v;
}

// ---- W fragment window: half-chunk (kk group g: 4 kk, hi+lo) --------------------------
__device__ __forceinline__ void loadW(short8 (&W)[8], const char* __restrict__ img,
                                      int c, int g, int lane) {
  const char* cb = img + (size_t)c * 16384 + lane * 16;
#pragma unroll
  for (int q = 0; q < 4; ++q) {
    W[2 * q]     = *(const short8*)(cb + (4 * g + q) * 1024);          // hi
    W[2 * q + 1] = *(const short8*)(cb + 8192 + (4 * g + q) * 1024);   // lo
  }
}

__device__ __forceinline__ void mfma4(const short8 (&W)[8], int g,
                                      const uint4v (&Bh)[8], const uint4v (&Bl)[8],
                                      f32x16 &aA, f32x16 &aB) {
#pragma unroll
  for (int q = 0; q < 4; ++q) {
    const int kk = 4 * g + q;
    if ((kk & 1) == 0) {
      aA = __builtin_amdgcn_mfma_f32_32x32x16_bf16(W[2 * q],     u2s(Bh[kk]), aA, 0, 0, 0);
      aA = __builtin_amdgcn_mfma_f32_32x32x16_bf16(W[2 * q],     u2s(Bl[kk]), aA, 0, 0, 0);
      aA = __builtin_amdgcn_mfma_f32_32x32x16_bf16(W[2 * q + 1], u2s(Bh[kk]), aA, 0, 0, 0);
    } else {
      aB = __builtin_amdgcn_mfma_f32_32x32x16_bf16(W[2 * q],     u2s(Bh[kk]), aB, 0, 0, 0);
      aB = __builtin_amdgcn_mfma_f32_32x32x16_bf16(W[2 * q],     u2s(Bl[kk]), aB, 0, 0, 0);
      aB = __builtin_amdgcn_mfma_f32_32x32x16_bf16(W[2 * q + 1], u2s(Bh[kk]), aB, 0, 0, 0);
    }
  }
}

// ---- one chunk's accumulators -> two B fragments of the next layer --------------------
template <bool RELU>
__device__ __forceinline__ void cvt_chunk(int mf, const f32x16 &aA, const f32x16 &aB,
                                          uint4v (&Bh)[8], uint4v (&Bl)[8]) {
#pragma unroll
  for (int s = 0; s < 2; ++s) {
    unsigned hu[8], lu[8];
#pragma unroll
    for (int i = 0; i < 8; ++i) {
      float v = aA[8 * s + i] + aB[8 * s + i];
      if (RELU) v = fmaxf(v, 0.0f);
      unsigned u = __float_as_uint(v);
      unsigned h = u & 0xFFFF0000u;
      hu[i] = h;
      lu[i] = __float_as_uint(v - __uint_as_float(h));
    }
    unsigned a0 = (hu[0] >> 16) | hu[1], a1 = (hu[2] >> 16) | hu[3];
    unsigned a2 = (hu[4] >> 16) | hu[5], a3 = (hu[6] >> 16) | hu[7];
    plswap(a0, a2); plswap(a1, a3);
    unsigned c0 = (lu[0] >> 16) | (lu[1] & 0xFFFF0000u), c1 = (lu[2] >> 16) | (lu[3] & 0xFFFF0000u);
    unsigned c2 = (lu[4] >> 16) | (lu[5] & 0xFFFF0000u), c3 = (lu[6] >> 16) | (lu[7] & 0xFFFF0000u);
    plswap(c0, c2); plswap(c1, c3);
    Bh[2 * mf + s] = uint4v{a0, a1, a2, a3};
    Bl[2 * mf + s] = uint4v{c0, c1, c2, c3};
  }
}

// ---- one layer (MF chunks), W double-buffer flows through -----------------------------
template <int MF, bool BIAS, typename EmitF>
__device__ __forceinline__ void layer(const char* __restrict__ img, int cbase, const float* bias,
                                      const uint4v (&Bh)[8], const uint4v (&Bl)[8],
                                      short8 (&W0)[8], short8 (&W1)[8],
                                      int lane, int half, EmitF&& emit) {
#pragma unroll
  for (int mf = 0; mf < MF; ++mf) {
    const int c = cbase + mf;
    f32x16 aA, aB;
#pragma unroll
    for (int i = 0; i < 16; ++i) { aA[i] = 0.0f; aB[i] = 0.0f; }
    if (BIAS) {
#pragma unroll
      for (int q = 0; q < 4; ++q) {
        f32x4 bq = *(const f32x4*)(bias + mf * 32 + q * 8 + half * 4);
#pragma unroll
        for (int r = 0; r < 4; ++r) aA[4 * q + r] = bq[r];
      }
    }
    loadW(W1, img, c, 1, lane);             // 2nd half of this chunk (covered by 12 MFMAs)
    mfma4(W0, 0, Bh, Bl, aA, aB);
    const int cn = (c + 1 < NCHUNKS) ? c + 1 : c;
    loadW(W0, img, cn, 0, lane);            // 1st half of next chunk
    mfma4(W1, 1, Bh, Bl, aA, aB);
    emit(mf, aA, aB);
  }
}

// ---- main fused kernel: barrier-free, LDS only for wave-private transpose -------------
__global__ __launch_bounds__(256, 2)
void ens_mlp(const float* __restrict__ x,  const float* __restrict__ b1,
             const float* __restrict__ b2, const float* __restrict__ b3,
             const char* __restrict__ img, float* __restrict__ out) {
  __shared__ float ybuf[128][37];   // wave-private rows [wv*32, wv*32+32)
  __shared__ float accb[256][19];   // per-thread sm[9]/sv[9]

  const int tid  = threadIdx.x;
  const int lane = tid & 63;
  const int wv   = tid >> 6;
  const int l31  = lane & 31;
  const int half = lane >> 5;
  const int b_loc = wv * 32 + l31;
  const size_t b_glob = (size_t)blockIdx.x * 128 + b_loc;

#pragma unroll
  for (int i = 0; i < 18; ++i) accb[tid][i] = 0.0f;

  short8 W0[8], W1[8];
  loadW(W0, img, 0, 0, lane);       // prologue: chunk 0 first half

  for (int m = 0; m < NM; ++m) {
    const int c0 = m * 10;

    // rebuild x fragments each model (x slice is L2-hot; frees 64 persistent VGPRs)
    uint4v Xh[8], Xl[8];
    {
      const float* xrow = x + b_glob * 128 + half * 8;
#pragma unroll
      for (int kk = 0; kk < 8; ++kk) {
        f32x4 f0 = *(const f32x4*)(xrow + kk * 16);
        f32x4 f1 = *(const f32x4*)(xrow + kk * 16 + 4);
        float f[8] = {f0[0], f0[1], f0[2], f0[3], f1[0], f1[1], f1[2], f1[3]};
        uint4v hw, lw;
#pragma unroll
        for (int jj = 0; jj < 4; ++jj) {
          unsigned ua = __float_as_uint(f[2 * jj]), ub = __float_as_uint(f[2 * jj + 1]);
          unsigned ha = ua & 0xFFFF0000u, hb = ub & 0xFFFF0000u;
          float la = f[2 * jj] - __uint_as_float(ha);
          float lb = f[2 * jj + 1] - __uint_as_float(hb);
          hw[jj] = (ha >> 16) | hb;
          lw[jj] = (__float_as_uint(la) >> 16) | (__float_as_uint(lb) & 0xFFFF0000u);
        }
        Xh[kk] = hw; Xl[kk] = lw;
      }
    }

    uint4v B2h[8], B2l[8];
    layer<4, true>(img, c0, b1 + m * 128, Xh, Xl, W0, W1, lane, half,
      [&](int mf, const f32x16 &aA, const f32x16 &aB) {
        cvt_chunk<true>(mf, aA, aB, B2h, B2l);
      });

    uint4v B3h[8], B3l[8];
    layer<4, true>(img, c0 + 4, b2 + m * 128, B2h, B2l, W0, W1, lane, half,
      [&](int mf, const f32x16 &aA, const f32x16 &aB) {
        cvt_chunk<true>(mf, aA, aB, B3h, B3l);
      });

    layer<2, false>(img, c0 + 8, (const float*)nullptr, B3h, B3l, W0, W1, lane, half,
      [&](int mf, const f32x16 &aA, const f32x16 &aB) {
        if (mf == 0) {
#pragma unroll
          for (int i = 0; i < 16; ++i) {
            int o = (i & 3) + 8 * (i >> 2) + 4 * half;     // 0..31
            ybuf[b_loc][o] = aA[i] + aB[i];
          }
        } else if (half == 0) {
#pragma unroll
          for (int i = 0; i < 4; ++i) ybuf[b_loc][32 + i] = aA[i] + aB[i];  // 32..35
        }
      });

    // wave-private epilogue: our 32 rows only — no __syncthreads anywhere
    asm volatile("s_waitcnt lgkmcnt(0)" ::: "memory");
    __builtin_amdgcn_sched_barrier(0);
    const float* b3m = b3 + m * 36;
#pragma unroll
    for (int i = 0; i < 9; ++i) {
      int e = lane + 64 * i;            // 576 = 32 rows * 18 outputs per wave
      int r = e / 18, o = e - 18 * r;
      float ym = ybuf[wv * 32 + r][o] + b3m[o];
      float yv = ybuf[wv * 32 + r][o + 18] + b3m[o + 18];
      float sp = fmaxf(yv, 0.0f) + log1pf(expf(-fabsf(yv)));
      accb[tid][i]     += ym;
      accb[tid][9 + i] += sp + 1e-6f + ym * ym;
    }
  }

#pragma unroll
  for (int i = 0; i < 9; ++i) {
    int e = lane + 64 * i;
    int r = e / 18, o = e - 18 * r;
    size_t row = (size_t)blockIdx.x * 128 + wv * 32 + r;
    float mean = accb[tid][i] * 0.2f;
    float var  = fmaxf(accb[tid][9 + i] * 0.2f - mean * mean, 0.0f) + 1e-6f;
    out[row * 18 + o] = mean;
    out[(size_t)NBATCH * 18 + row * 18 + o] = var;
  }
}

// ---- launcher -------------------------------------------------------------------------
extern "C" void kernel_launch(void* const* d_in, const int* in_sizes, int n_in,
                              void* d_out, int out_size, void* d_ws, size_t ws_size,
                              hipStream_t stream) {
  const float* x  = (const float*)d_in[0];
  const float* W1 = (const float*)d_in[1];
  const float* b1 = (const float*)d_in[2];
  const float* W2 = (const float*)d_in[3];
  const float* b2 = (const float*)d_in[4];
  const float* W3 = (const float*)d_in[5];
  const float* b3 = (const float*)d_in[6];
  char* img = (char*)d_ws;   // 819,200 B of workspace

  hipLaunchKernelGGL(prep_weights, dim3(100), dim3(256), 0, stream, W1, W2, W3, img);
  hipLaunchKernelGGL(ens_mlp, dim3(512), dim3(256), 0, stream,
                     x, b1, b2, b3, (const char*)img, (float*)d_out);
}

// Round 5
// 222.299 us; speedup vs baseline: 1.0340x; 1.0340x over previous
//
#include <hip/hip_runtime.h>
#include <math.h>

#define NM 5
#define NBATCH 65536
#define NCHUNKS 50         // 5 models * 10 chunks (4 W1, 4 W2, 2 W3-padded)

typedef float f32x16 __attribute__((ext_vector_type(16)));
typedef float f32x4  __attribute__((ext_vector_type(4)));
typedef short short8 __attribute__((ext_vector_type(8)));
typedef unsigned int uint4v __attribute__((ext_vector_type(4)));
typedef unsigned int uint2v __attribute__((ext_vector_type(2)));

__device__ __forceinline__ short8 u2s(uint4v v) { union { uint4v u; short8 s; } t; t.u = v; return t.s; }

__device__ __forceinline__ void plswap(unsigned &a, unsigned &b) {
#if __has_builtin(__builtin_amdgcn_permlane32_swap)
  uint2v r = __builtin_amdgcn_permlane32_swap(a, b, false, false);
  a = r[0]; b = r[1];
#else
  unsigned ta = (unsigned)__shfl_xor((int)a, 32, 64);
  unsigned tb = (unsigned)__shfl_xor((int)b, 32, 64);
  bool h0 = ((threadIdx.x & 63) < 32);
  unsigned na = h0 ? a : tb;
  unsigned nb = h0 ? ta : b;
  a = na; b = nb;
#endif
}

// ---- prep: weights -> per-lane A-fragment image (direct global-load layout) -----------
// chunk c10 (= m*10+c) is 16 KiB: [hi plane 8 KiB][lo plane 8 KiB];
// within a plane: frag(kk, lane) at kk*1024 + lane*16 holds W[row=lane&31][16kk+8*(lane>>5)+j]
__global__ void prep_weights(const float* __restrict__ W1, const float* __restrict__ W2,
                             const float* __restrict__ W3, char* __restrict__ img) {
  int id = blockIdx.x * 256 + threadIdx.x;       // one thread per (c10, kk, lane)
  if (id >= NCHUNKS * 8 * 64) return;
  int lane = id & 63; int kk = (id >> 6) & 7; int c10 = id >> 9;
  int m = c10 / 10, c = c10 % 10;
  int g_rel = lane & 31, half = lane >> 5;
  int k0 = kk * 16 + half * 8;
  const float* src = nullptr;
  if (c < 4)      { int g = c * 32 + g_rel;       src = W1 + ((size_t)m * 128 + g) * 128 + k0; }
  else if (c < 8) { int g = (c - 4) * 32 + g_rel; src = W2 + ((size_t)m * 128 + g) * 128 + k0; }
  else            { int g = (c - 8) * 32 + g_rel; if (g < 36) src = W3 + ((size_t)m * 36 + g) * 128 + k0; }
  union { short8 v; unsigned short s[8]; } hi, lo;
#pragma unroll
  for (int j = 0; j < 8; ++j) {
    float v = src ? src[j] : 0.0f;
    unsigned u = __float_as_uint(v);
    unsigned h = u & 0xFFFF0000u;
    float l = v - __uint_as_float(h);
    hi.s[j] = (unsigned short)(h >> 16);
    lo.s[j] = (unsigned short)(__float_as_uint(l) >> 16);
  }
  char* dst = img + (size_t)c10 * 16384 + kk * 1024 + lane * 16;
  *(short8*)dst = hi.v;
  *(short8*)(dst + 8192) = lo.v;
}

// ---- W fragment window: half-chunk (kk group g: 4 kk, hi+lo) --------------------------
__device__ __forceinline__ void loadW(short8 (&W)[8], const char* __restrict__ img,
                                      int c, int g, int lane) {
  const char* cb = img + (size_t)c * 16384 + lane * 16;
#pragma unroll
  for (int q = 0; q < 4; ++q) {
    W[2 * q]     = *(const short8*)(cb + (4 * g + q) * 1024);          // hi
    W[2 * q + 1] = *(const short8*)(cb + 8192 + (4 * g + q) * 1024);   // lo
  }
}

__device__ __forceinline__ void mfma4(const short8 (&W)[8], int g,
                                      const uint4v (&Bh)[8], const uint4v (&Bl)[8],
                                      f32x16 &aA, f32x16 &aB) {
#pragma unroll
  for (int q = 0; q < 4; ++q) {
    const int kk = 4 * g + q;
    if ((kk & 1) == 0) {
      aA = __builtin_amdgcn_mfma_f32_32x32x16_bf16(W[2 * q],     u2s(Bh[kk]), aA, 0, 0, 0);
      aA = __builtin_amdgcn_mfma_f32_32x32x16_bf16(W[2 * q],     u2s(Bl[kk]), aA, 0, 0, 0);
      aA = __builtin_amdgcn_mfma_f32_32x32x16_bf16(W[2 * q + 1], u2s(Bh[kk]), aA, 0, 0, 0);
    } else {
      aB = __builtin_amdgcn_mfma_f32_32x32x16_bf16(W[2 * q],     u2s(Bh[kk]), aB, 0, 0, 0);
      aB = __builtin_amdgcn_mfma_f32_32x32x16_bf16(W[2 * q],     u2s(Bl[kk]), aB, 0, 0, 0);
      aB = __builtin_amdgcn_mfma_f32_32x32x16_bf16(W[2 * q + 1], u2s(Bh[kk]), aB, 0, 0, 0);
    }
  }
}

// ---- one chunk's accumulators -> two B fragments of the next layer --------------------
template <bool RELU>
__device__ __forceinline__ void cvt_chunk(int mf, const f32x16 &aA, const f32x16 &aB,
                                          uint4v (&Bh)[8], uint4v (&Bl)[8]) {
#pragma unroll
  for (int s = 0; s < 2; ++s) {
    unsigned hu[8], lu[8];
#pragma unroll
    for (int i = 0; i < 8; ++i) {
      float v = aA[8 * s + i] + aB[8 * s + i];
      if (RELU) v = fmaxf(v, 0.0f);
      unsigned u = __float_as_uint(v);
      unsigned h = u & 0xFFFF0000u;
      hu[i] = h;
      lu[i] = __float_as_uint(v - __uint_as_float(h));
    }
    unsigned a0 = (hu[0] >> 16) | hu[1], a1 = (hu[2] >> 16) | hu[3];
    unsigned a2 = (hu[4] >> 16) | hu[5], a3 = (hu[6] >> 16) | hu[7];
    plswap(a0, a2); plswap(a1, a3);
    unsigned c0 = (lu[0] >> 16) | (lu[1] & 0xFFFF0000u), c1 = (lu[2] >> 16) | (lu[3] & 0xFFFF0000u);
    unsigned c2 = (lu[4] >> 16) | (lu[5] & 0xFFFF0000u), c3 = (lu[6] >> 16) | (lu[7] & 0xFFFF0000u);
    plswap(c0, c2); plswap(c1, c3);
    Bh[2 * mf + s] = uint4v{a0, a1, a2, a3};
    Bl[2 * mf + s] = uint4v{c0, c1, c2, c3};
  }
}

// ---- one layer (MF chunks), W double-buffer flows through -----------------------------
template <int MF, bool BIAS, typename EmitF>
__device__ __forceinline__ void layer(const char* __restrict__ img, int cbase, const float* bias,
                                      const uint4v (&Bh)[8], const uint4v (&Bl)[8],
                                      short8 (&W0)[8], short8 (&W1)[8],
                                      int lane, int half, EmitF&& emit) {
#pragma unroll
  for (int mf = 0; mf < MF; ++mf) {
    const int c = cbase + mf;
    f32x16 aA, aB;
#pragma unroll
    for (int i = 0; i < 16; ++i) { aA[i] = 0.0f; aB[i] = 0.0f; }
    if (BIAS) {
#pragma unroll
      for (int q = 0; q < 4; ++q) {
        f32x4 bq = *(const f32x4*)(bias + mf * 32 + q * 8 + half * 4);
#pragma unroll
        for (int r = 0; r < 4; ++r) aA[4 * q + r] = bq[r];
      }
    }
    loadW(W1, img, c, 1, lane);             // 2nd half of this chunk (covered by 12 MFMAs)
    mfma4(W0, 0, Bh, Bl, aA, aB);
    const int cn = (c + 1 < NCHUNKS) ? c + 1 : c;
    loadW(W0, img, cn, 0, lane);            // 1st half of next chunk
    mfma4(W1, 1, Bh, Bl, aA, aB);
    emit(mf, aA, aB);
  }
}

// ---- main fused kernel: 1 wave per block, barrier-free --------------------------------
__global__ __launch_bounds__(64)
void ens_mlp(const float* __restrict__ x,  const float* __restrict__ b1,
             const float* __restrict__ b2, const float* __restrict__ b3,
             const char* __restrict__ img, float* __restrict__ out) {
  __shared__ float ybuf[32][37];    // this wave's 32 batch rows (transpose buffer)
  __shared__ float accb[64][19];    // per-thread sm[9]/sv[9]

  const int lane = threadIdx.x & 63;
  const int l31  = lane & 31;
  const int half = lane >> 5;
  const size_t b_glob = (size_t)blockIdx.x * 32 + l31;

#pragma unroll
  for (int i = 0; i < 18; ++i) accb[lane][i] = 0.0f;

  short8 W0[8], W1[8];
  loadW(W0, img, 0, 0, lane);       // prologue: chunk 0 first half

#pragma unroll 1
  for (int m = 0; m < NM; ++m) {
    const int c0 = m * 10;

    // rebuild x fragments each model (L1/L2-hot; avoids 64 persistent VGPRs)
    uint4v Xh[8], Xl[8];
    {
      const float* xrow = x + b_glob * 128 + half * 8;
#pragma unroll
      for (int kk = 0; kk < 8; ++kk) {
        f32x4 f0 = *(const f32x4*)(xrow + kk * 16);
        f32x4 f1 = *(const f32x4*)(xrow + kk * 16 + 4);
        float f[8] = {f0[0], f0[1], f0[2], f0[3], f1[0], f1[1], f1[2], f1[3]};
        uint4v hw, lw;
#pragma unroll
        for (int jj = 0; jj < 4; ++jj) {
          unsigned ua = __float_as_uint(f[2 * jj]), ub = __float_as_uint(f[2 * jj + 1]);
          unsigned ha = ua & 0xFFFF0000u, hb = ub & 0xFFFF0000u;
          float la = f[2 * jj] - __uint_as_float(ha);
          float lb = f[2 * jj + 1] - __uint_as_float(hb);
          hw[jj] = (ha >> 16) | hb;
          lw[jj] = (__float_as_uint(la) >> 16) | (__float_as_uint(lb) & 0xFFFF0000u);
        }
        Xh[kk] = hw; Xl[kk] = lw;
      }
    }

    uint4v B2h[8], B2l[8];
    layer<4, true>(img, c0, b1 + m * 128, Xh, Xl, W0, W1, lane, half,
      [&](int mf, const f32x16 &aA, const f32x16 &aB) {
        cvt_chunk<true>(mf, aA, aB, B2h, B2l);
      });

    uint4v B3h[8], B3l[8];
    layer<4, true>(img, c0 + 4, b2 + m * 128, B2h, B2l, W0, W1, lane, half,
      [&](int mf, const f32x16 &aA, const f32x16 &aB) {
        cvt_chunk<true>(mf, aA, aB, B3h, B3l);
      });

    layer<2, false>(img, c0 + 8, (const float*)nullptr, B3h, B3l, W0, W1, lane, half,
      [&](int mf, const f32x16 &aA, const f32x16 &aB) {
        if (mf == 0) {
#pragma unroll
          for (int i = 0; i < 16; ++i) {
            int o = (i & 3) + 8 * (i >> 2) + 4 * half;     // 0..31
            ybuf[l31][o] = aA[i] + aB[i];
          }
        } else if (half == 0) {
#pragma unroll
          for (int i = 0; i < 4; ++i) ybuf[l31][32 + i] = aA[i] + aB[i];  // 32..35
        }
      });

    // wave-private epilogue (single wave per block — no barrier needed, just LDS drain)
    asm volatile("s_waitcnt lgkmcnt(0)" ::: "memory");
    __builtin_amdgcn_sched_barrier(0);
    const float* b3m = b3 + m * 36;
#pragma unroll
    for (int i = 0; i < 9; ++i) {
      int e = lane + 64 * i;            // 576 = 32 rows * 18 outputs
      int r = e / 18, o = e - 18 * r;
      float ym = ybuf[r][o] + b3m[o];
      float yv = ybuf[r][o + 18] + b3m[o + 18];
      float sp = fmaxf(yv, 0.0f) + log1pf(expf(-fabsf(yv)));
      accb[lane][i]     += ym;
      accb[lane][9 + i] += sp + 1e-6f + ym * ym;
    }
  }

#pragma unroll
  for (int i = 0; i < 9; ++i) {
    int e = lane + 64 * i;
    int r = e / 18, o = e - 18 * r;
    size_t row = (size_t)blockIdx.x * 32 + r;
    float mean = accb[lane][i] * 0.2f;
    float var  = fmaxf(accb[lane][9 + i] * 0.2f - mean * mean, 0.0f) + 1e-6f;
    out[row * 18 + o] = mean;
    out[(size_t)NBATCH * 18 + row * 18 + o] = var;
  }
}

// ---- launcher -------------------------------------------------------------------------
extern "C" void kernel_launch(void* const* d_in, const int* in_sizes, int n_in,
                              void* d_out, int out_size, void* d_ws, size_t ws_size,
                              hipStream_t stream) {
  const float* x  = (const float*)d_in[0];
  const float* W1 = (const float*)d_in[1];
  const float* b1 = (const float*)d_in[2];
  const float* W2 = (const float*)d_in[3];
  const float* b2 = (const float*)d_in[4];
  const float* W3 = (const float*)d_in[5];
  const float* b3 = (const float*)d_in[6];
  char* img = (char*)d_ws;   // 819,200 B of workspace

  hipLaunchKernelGGL(prep_weights, dim3(100), dim3(256), 0, stream, W1, W2, W3, img);
  hipLaunchKernelGGL(ens_mlp, dim3(2048), dim3(64), 0, stream,
                     x, b1, b2, b3, (const char*)img, (float*)d_out);
}

// Round 6
// 204.012 us; speedup vs baseline: 1.1267x; 1.0896x over previous
//
#include <hip/hip_runtime.h>
#include <math.h>

#define NM 5
#define NBATCH 65536
#define NCHUNKS 50         // 5 models * 10 chunks (4 W1, 4 W2, 2 W3-padded)

typedef float f32x16 __attribute__((ext_vector_type(16)));
typedef float f32x4  __attribute__((ext_vector_type(4)));
typedef short short8 __attribute__((ext_vector_type(8)));
typedef unsigned int uint4v __attribute__((ext_vector_type(4)));
typedef unsigned int uint2v __attribute__((ext_vector_type(2)));

__device__ __forceinline__ short8 u2s(uint4v v) { union { uint4v u; short8 s; } t; t.u = v; return t.s; }

__device__ __forceinline__ void plswap(unsigned &a, unsigned &b) {
#if __has_builtin(__builtin_amdgcn_permlane32_swap)
  uint2v r = __builtin_amdgcn_permlane32_swap(a, b, false, false);
  a = r[0]; b = r[1];
#else
  unsigned ta = (unsigned)__shfl_xor((int)a, 32, 64);
  unsigned tb = (unsigned)__shfl_xor((int)b, 32, 64);
  bool h0 = ((threadIdx.x & 63) < 32);
  unsigned na = h0 ? a : tb;
  unsigned nb = h0 ? ta : b;
  a = na; b = nb;
#endif
}

// ---- prep: weights -> per-lane A-fragment image (fragment-linear layout) --------------
// chunk c10 (= m*10+c) is 16 KiB: [hi plane 8 KiB][lo plane 8 KiB];
// plane: frag(kk, lane) at kk*1024 + lane*16 holds W[row=lane&31][16kk+8*(lane>>5)+j]
__global__ void prep_weights(const float* __restrict__ W1, const float* __restrict__ W2,
                             const float* __restrict__ W3, char* __restrict__ img) {
  int id = blockIdx.x * 256 + threadIdx.x;       // one thread per (c10, kk, lane)
  if (id >= NCHUNKS * 8 * 64) return;
  int lane = id & 63; int kk = (id >> 6) & 7; int c10 = id >> 9;
  int m = c10 / 10, c = c10 % 10;
  int g_rel = lane & 31, half = lane >> 5;
  int k0 = kk * 16 + half * 8;
  const float* src = nullptr;
  if (c < 4)      { int g = c * 32 + g_rel;       src = W1 + ((size_t)m * 128 + g) * 128 + k0; }
  else if (c < 8) { int g = (c - 4) * 32 + g_rel; src = W2 + ((size_t)m * 128 + g) * 128 + k0; }
  else            { int g = (c - 8) * 32 + g_rel; if (g < 36) src = W3 + ((size_t)m * 36 + g) * 128 + k0; }
  union { short8 v; unsigned short s[8]; } hi, lo;
#pragma unroll
  for (int j = 0; j < 8; ++j) {
    float v = src ? src[j] : 0.0f;
    unsigned u = __float_as_uint(v);
    unsigned h = u & 0xFFFF0000u;
    float l = v - __uint_as_float(h);
    hi.s[j] = (unsigned short)(h >> 16);
    lo.s[j] = (unsigned short)(__float_as_uint(l) >> 16);
  }
  char* dst = img + (size_t)c10 * 16384 + kk * 1024 + lane * 16;
  *(short8*)dst = hi.v;
  *(short8*)(dst + 8192) = lo.v;
}

// ---- one chunk's accumulators -> two B fragments of the next layer --------------------
template <bool RELU>
__device__ __forceinline__ void cvt_chunk(int mf, const f32x16 &aA, const f32x16 &aB,
                                          uint4v (&Bh)[8], uint4v (&Bl)[8]) {
#pragma unroll
  for (int s = 0; s < 2; ++s) {
    unsigned hu[8], lu[8];
#pragma unroll
    for (int i = 0; i < 8; ++i) {
      float v = aA[8 * s + i] + aB[8 * s + i];
      if (RELU) v = fmaxf(v, 0.0f);
      unsigned u = __float_as_uint(v);
      unsigned h = u & 0xFFFF0000u;
      hu[i] = h;
      lu[i] = __float_as_uint(v - __uint_as_float(h));
    }
    unsigned a0 = (hu[0] >> 16) | hu[1], a1 = (hu[2] >> 16) | hu[3];
    unsigned a2 = (hu[4] >> 16) | hu[5], a3 = (hu[6] >> 16) | hu[7];
    plswap(a0, a2); plswap(a1, a3);
    unsigned c0 = (lu[0] >> 16) | (lu[1] & 0xFFFF0000u), c1 = (lu[2] >> 16) | (lu[3] & 0xFFFF0000u);
    unsigned c2 = (lu[4] >> 16) | (lu[5] & 0xFFFF0000u), c3 = (lu[6] >> 16) | (lu[7] & 0xFFFF0000u);
    plswap(c0, c2); plswap(c1, c3);
    Bh[2 * mf + s] = uint4v{a0, a1, a2, a3};
    Bl[2 * mf + s] = uint4v{c0, c1, c2, c3};
  }
}

// ---- one layer: MF chunks, W streamed from LDS double-buffer --------------------------
// wbuf holds chunk c in wbuf[c&1]; stage() prefetches c+1 into wbuf[(c+1)&1];
// __syncthreads at chunk end drains the staged loads and releases the old buffer.
template <int MF, bool BIAS, typename StageF, typename EmitF>
__device__ __forceinline__ void run_layer(int cbase, const float* bias,
                                          const uint4v (&Bh)[8], const uint4v (&Bl)[8],
                                          const char* wb0, const char* wb1,
                                          int half, StageF&& stage, EmitF&& emit) {
#pragma unroll
  for (int mf = 0; mf < MF; ++mf) {
    const int c = cbase + mf;
    stage(c + 1);
    f32x16 aA, aB;
#pragma unroll
    for (int i = 0; i < 16; ++i) { aA[i] = 0.0f; aB[i] = 0.0f; }
    if (BIAS) {
#pragma unroll
      for (int q = 0; q < 4; ++q) {     // C row = (i&3) + 8*(i>>2) + 4*half
        f32x4 bq = *(const f32x4*)(bias + mf * 32 + q * 8 + half * 4);
#pragma unroll
        for (int r = 0; r < 4; ++r) aA[4 * q + r] = bq[r];
      }
    }
    const char* wb = (c & 1) ? wb1 : wb0;   // + lane*16 already folded in by caller
#pragma unroll
    for (int kk = 0; kk < 8; ++kk) {
      short8 Wh = *(const short8*)(wb + kk * 1024);
      short8 Wl = *(const short8*)(wb + kk * 1024 + 8192);
      if ((kk & 1) == 0) {
        aA = __builtin_amdgcn_mfma_f32_32x32x16_bf16(Wh, u2s(Bh[kk]), aA, 0, 0, 0);
        aA = __builtin_amdgcn_mfma_f32_32x32x16_bf16(Wh, u2s(Bl[kk]), aA, 0, 0, 0);
        aA = __builtin_amdgcn_mfma_f32_32x32x16_bf16(Wl, u2s(Bh[kk]), aA, 0, 0, 0);
      } else {
        aB = __builtin_amdgcn_mfma_f32_32x32x16_bf16(Wh, u2s(Bh[kk]), aB, 0, 0, 0);
        aB = __builtin_amdgcn_mfma_f32_32x32x16_bf16(Wh, u2s(Bl[kk]), aB, 0, 0, 0);
        aB = __builtin_amdgcn_mfma_f32_32x32x16_bf16(Wl, u2s(Bh[kk]), aB, 0, 0, 0);
      }
    }
    emit(mf, aA, aB);
    __syncthreads();
  }
}

// ---- main fused kernel: 4 waves share one W stream through LDS ------------------------
__global__ __launch_bounds__(256)
void ens_mlp(const float* __restrict__ x,  const float* __restrict__ b1,
             const float* __restrict__ b2, const float* __restrict__ b3,
             const char* __restrict__ img, float* __restrict__ out) {
  __shared__ __align__(16) char wbuf[2][16384];   // 32 KiB W-chunk double buffer (shared)
  __shared__ float ybuf[128][37];                 // per-wave 32-row slices (padded)
  __shared__ float accb[256][19];                 // per-thread sm[9]/sv[9]

  const int tid  = threadIdx.x;
  const int lane = tid & 63;
  const int wv   = tid >> 6;
  const int l31  = lane & 31;
  const int half = lane >> 5;
  const int b_loc = wv * 32 + l31;
  const size_t b_glob = (size_t)blockIdx.x * 128 + b_loc;

  auto stage = [&](int j) {
    if (j >= NCHUNKS) return;
    const char* src = img + (size_t)j * 16384;
    char* dst = &wbuf[j & 1][0];
#pragma unroll
    for (int i = 0; i < 4; ++i) {
      int off = i * 4096 + wv * 1024;   // dest: wave-uniform base + lane*16 (linear image)
      __builtin_amdgcn_global_load_lds(
          (const __attribute__((address_space(1))) unsigned int*)(src + off + lane * 16),
          (__attribute__((address_space(3))) unsigned int*)(dst + off),
          16, 0, 0);
    }
  };

  const char* wb0 = &wbuf[0][0] + lane * 16;
  const char* wb1 = &wbuf[1][0] + lane * 16;

#pragma unroll
  for (int i = 0; i < 18; ++i) accb[tid][i] = 0.0f;

  stage(0);
  __syncthreads();   // chunk 0 ready

#pragma unroll 1
  for (int m = 0; m < NM; ++m) {
    const int c0 = m * 10;

    // rebuild x fragments each model (L2-hot; avoids 64 persistent VGPRs)
    uint4v Xh[8], Xl[8];
    {
      const float* xrow = x + b_glob * 128 + half * 8;
#pragma unroll
      for (int kk = 0; kk < 8; ++kk) {
        f32x4 f0 = *(const f32x4*)(xrow + kk * 16);
        f32x4 f1 = *(const f32x4*)(xrow + kk * 16 + 4);
        float f[8] = {f0[0], f0[1], f0[2], f0[3], f1[0], f1[1], f1[2], f1[3]};
        uint4v hw, lw;
#pragma unroll
        for (int jj = 0; jj < 4; ++jj) {
          unsigned ua = __float_as_uint(f[2 * jj]), ub = __float_as_uint(f[2 * jj + 1]);
          unsigned ha = ua & 0xFFFF0000u, hb = ub & 0xFFFF0000u;
          float la = f[2 * jj] - __uint_as_float(ha);
          float lb = f[2 * jj + 1] - __uint_as_float(hb);
          hw[jj] = (ha >> 16) | hb;
          lw[jj] = (__float_as_uint(la) >> 16) | (__float_as_uint(lb) & 0xFFFF0000u);
        }
        Xh[kk] = hw; Xl[kk] = lw;
      }
    }

    uint4v B2h[8], B2l[8];
    run_layer<4, true>(c0, b1 + m * 128, Xh, Xl, wb0, wb1, half, stage,
      [&](int mf, const f32x16 &aA, const f32x16 &aB) {
        cvt_chunk<true>(mf, aA, aB, B2h, B2l);
      });

    uint4v B3h[8], B3l[8];
    run_layer<4, true>(c0 + 4, b2 + m * 128, B2h, B2l, wb0, wb1, half, stage,
      [&](int mf, const f32x16 &aA, const f32x16 &aB) {
        cvt_chunk<true>(mf, aA, aB, B3h, B3l);
      });

    run_layer<2, false>(c0 + 8, (const float*)nullptr, B3h, B3l, wb0, wb1, half, stage,
      [&](int mf, const f32x16 &aA, const f32x16 &aB) {
        if (mf == 0) {
#pragma unroll
          for (int i = 0; i < 16; ++i) {
            int o = (i & 3) + 8 * (i >> 2) + 4 * half;     // 0..31
            ybuf[b_loc][o] = aA[i] + aB[i];
          }
        } else if (half == 0) {
#pragma unroll
          for (int i = 0; i < 4; ++i) ybuf[b_loc][32 + i] = aA[i] + aB[i];  // 32..35
        }
      });

    // wave-private epilogue: our 32 rows only (no cross-wave data -> no barrier)
    asm volatile("s_waitcnt lgkmcnt(0)" ::: "memory");
    __builtin_amdgcn_sched_barrier(0);
    const float* b3m = b3 + m * 36;
#pragma unroll
    for (int i = 0; i < 9; ++i) {
      int e = lane + 64 * i;            // 576 = 32 rows * 18 outputs per wave
      int r = e / 18, o = e - 18 * r;
      float ym = ybuf[wv * 32 + r][o] + b3m[o];
      float yv = ybuf[wv * 32 + r][o + 18] + b3m[o + 18];
      float sp = fmaxf(yv, 0.0f) + log1pf(expf(-fabsf(yv)));   // stable softplus
      accb[tid][i]     += ym;
      accb[tid][9 + i] += sp + 1e-6f + ym * ym;
    }
  }

#pragma unroll
  for (int i = 0; i < 9; ++i) {
    int e = lane + 64 * i;
    int r = e / 18, o = e - 18 * r;
    size_t row = (size_t)blockIdx.x * 128 + wv * 32 + r;
    float mean = accb[tid][i] * 0.2f;
    float var  = fmaxf(accb[tid][9 + i] * 0.2f - mean * mean, 0.0f) + 1e-6f;
    out[row * 18 + o] = mean;
    out[(size_t)NBATCH * 18 + row * 18 + o] = var;
  }
}

// ---- launcher -------------------------------------------------------------------------
extern "C" void kernel_launch(void* const* d_in, const int* in_sizes, int n_in,
                              void* d_out, int out_size, void* d_ws, size_t ws_size,
                              hipStream_t stream) {
  const float* x  = (const float*)d_in[0];
  const float* W1 = (const float*)d_in[1];
  const float* b1 = (const float*)d_in[2];
  const float* W2 = (const float*)d_in[3];
  const float* b2 = (const float*)d_in[4];
  const float* W3 = (const float*)d_in[5];
  const float* b3 = (const float*)d_in[6];
  char* img = (char*)d_ws;   // 819,200 B of workspace

  hipLaunchKernelGGL(prep_weights, dim3(100), dim3(256), 0, stream, W1, W2, W3, img);
  hipLaunchKernelGGL(ens_mlp, dim3(512), dim3(256), 0, stream,
                     x, b1, b2, b3, (const char*)img, (float*)d_out);
}